// Round 7
// baseline (269.282 us; speedup 1.0000x reference)
//
#include <hip/hip_runtime.h>

// Problem constants
#define B_ 32
#define N_ 4096
#define C_ 768
#define H_ 8
#define DH_ 96
#define TILE 8
#define ROWS 128
#define NT (ROWS / TILE)     // 16 tiles per chunk
#define NCH (N_ / ROWS)      // 32 chunks per batch row

struct F3 { float x, y, z; };

// barrier with LDS drain only (no vmem drain)
#define BARL() do { asm volatile("s_waitcnt lgkmcnt(0)" ::: "memory"); \
                    __builtin_amdgcn_s_barrier(); } while (0)

// ---- q[e] = sum_c queries[c] * Wq[e,c] ------------------------------------
__global__ void k_q(const float* __restrict__ queries, const float* __restrict__ Wq,
                    float* __restrict__ q) {
  int e = blockIdx.x;
  int lane = threadIdx.x;
  const float* row = Wq + (size_t)e * C_;
  float acc = 0.f;
#pragma unroll
  for (int p = 0; p < 3; ++p) {
    int c = p * 256 + lane * 4;
    float4 w = *(const float4*)(row + c);
    float4 qa = *(const float4*)(queries + c);
    acc += w.x * qa.x + w.y * qa.y + w.z * qa.z + w.w * qa.w;
  }
#pragma unroll
  for (int off = 32; off; off >>= 1) acc += __shfl_xor(acc, off);
  if (lane == 0) q[e] = acc;
}

// ---- wq_eff[h,c] = sum_d q[h*DH+d] * Wkv[h*DH+d, c] -----------------------
__global__ void k_wqeff(const float* __restrict__ q, const float* __restrict__ Wkv,
                        float* __restrict__ wqe) {
  int i = blockIdx.x * 256 + threadIdx.x;
  int h = i / C_;
  int c = i - h * C_;
  const float* qh = q + h * DH_;
  float acc = 0.f;
  for (int d = 0; d < DH_; ++d)
    acc = fmaf(qh[d], Wkv[(size_t)(h * DH_ + d) * C_ + c], acc);
  wqe[i] = acc;
}

// ---- single-pass fused: dots -> exp(d-20) -> weighted accumulate ----------
// grid (NCH, B_) = 1024 blocks, 256 threads (4 waves), 48.3 KB LDS ->
// 3 blocks/CU, 12 waves/CU. x staged to LDS via global_load_lds, read once
// from HBM, consumed twice from LDS (phase A: dots; phase C: accumulate).
// Wave wid owns heads {2*wid, 2*wid+1} in phase A (wq = 24 VGPR).
__global__ __launch_bounds__(256, 3) void k_fused(
    const float* __restrict__ x, const float* __restrict__ wqe,
    float* __restrict__ part, float* __restrict__ sout) {
  __shared__ __align__(16) float xbuf[2][TILE * C_];  // 48 KB double buffer
  __shared__ __align__(16) float swt[TILE][H_];       // 256 B exp weights

  const int ch = blockIdx.x, b = blockIdx.y;
  const int tid = threadIdx.x, lane = tid & 63, wid = tid >> 6;
  const int h0 = wid * 2;
  const int col = lane * 4;
  const int l1 = lane & 1;
  const float* xc = x + ((size_t)b * N_ + (size_t)ch * ROWS) * C_;

  // wq for this wave's two heads: 24 VGPR
  float4 wq0[3], wq1[3];
#pragma unroll
  for (int p = 0; p < 3; ++p) {
    wq0[p] = *(const float4*)(wqe + h0 * C_ + p * 256 + col);
    wq1[p] = *(const float4*)(wqe + (h0 + 1) * C_ + p * 256 + col);
  }

  // output accumulator: thread owns cols {tid*3..+2} for all 8 heads (24 VGPR)
  float acc[H_][3];
#pragma unroll
  for (int h = 0; h < H_; ++h) { acc[h][0] = 0.f; acc[h][1] = 0.f; acc[h][2] = 0.f; }
  float sreg = 0.f;   // even lanes: head h0 denom; odd lanes: head h0+1

#define STAGE(BUF, T) do {                                                     \
    const float* gt_ = xc + (size_t)(T) * TILE * C_;                           \
    float* bn_ = xbuf[BUF];                                                    \
    _Pragma("unroll")                                                          \
    for (int j = 0; j < 6; ++j) {                                              \
      int k = wid * 6 + j;                                                     \
      __builtin_amdgcn_global_load_lds(                                        \
        (const __attribute__((address_space(1))) void*)(gt_ + k * 256 + lane * 4), \
        (__attribute__((address_space(3))) void*)(bn_ + k * 256),              \
        16, 0, 0);                                                             \
    }                                                                          \
  } while (0)

  STAGE(0, 0);   // prologue

  for (int t = 0; t < NT; ++t) {
    const float* xb = xbuf[t & 1];
    // own tile-t loads done (vmcnt is per-wave!) ...
    asm volatile("s_waitcnt vmcnt(0)" ::: "memory");
    // ... then barrier: ALL waves' stage of tile t complete; C(t-1) done
    BARL();
    if (t + 1 < NT) STAGE((t + 1) & 1, t + 1);   // covered by phases A+C

    // ---- Phase A: 8 rows x this wave's 2 heads; w -> swt ------------------
#pragma unroll
    for (int r = 0; r < TILE; ++r) {
      const float* xr = xb + r * C_;
      float4 xv0 = *(const float4*)(xr + col);
      float4 xv1 = *(const float4*)(xr + 256 + col);
      float4 xv2 = *(const float4*)(xr + 512 + col);
      float a0, a1;
      a0  = xv0.x * wq0[0].x;            a1  = xv0.x * wq1[0].x;
      a0 = fmaf(xv0.y, wq0[0].y, a0);    a1 = fmaf(xv0.y, wq1[0].y, a1);
      a0 = fmaf(xv0.z, wq0[0].z, a0);    a1 = fmaf(xv0.z, wq1[0].z, a1);
      a0 = fmaf(xv0.w, wq0[0].w, a0);    a1 = fmaf(xv0.w, wq1[0].w, a1);
      a0 = fmaf(xv1.x, wq0[1].x, a0);    a1 = fmaf(xv1.x, wq1[1].x, a1);
      a0 = fmaf(xv1.y, wq0[1].y, a0);    a1 = fmaf(xv1.y, wq1[1].y, a1);
      a0 = fmaf(xv1.z, wq0[1].z, a0);    a1 = fmaf(xv1.z, wq1[1].z, a1);
      a0 = fmaf(xv1.w, wq0[1].w, a0);    a1 = fmaf(xv1.w, wq1[1].w, a1);
      a0 = fmaf(xv2.x, wq0[2].x, a0);    a1 = fmaf(xv2.x, wq1[2].x, a1);
      a0 = fmaf(xv2.y, wq0[2].y, a0);    a1 = fmaf(xv2.y, wq1[2].y, a1);
      a0 = fmaf(xv2.z, wq0[2].z, a0);    a1 = fmaf(xv2.z, wq1[2].z, a1);
      a0 = fmaf(xv2.w, wq0[2].w, a0);    a1 = fmaf(xv2.w, wq1[2].w, a1);
      // packed 2-head butterfly: even lanes end with head h0, odd with h0+1
      float u = l1 ? a1 : a0;
      float v = l1 ? a0 : a1;
      float s = u + __shfl_xor(v, 1);
      s += __shfl_xor(s, 2);
      s += __shfl_xor(s, 4);
      s += __shfl_xor(s, 8);
      s += __shfl_xor(s, 16);
      s += __shfl_xor(s, 32);
      float w = __expf(s - 20.f);
      sreg += w;
      if (lane < 2) swt[r][h0 + lane] = w;
    }
    BARL();   // swt published

    // ---- Phase C: acc[h][c-slice] += sum_r swt[r][h] * x[r][c-slice] ------
    {
      const int c0 = tid * 3;
#pragma unroll
      for (int r = 0; r < TILE; ++r) {
        float4 w0 = *(const float4*)(&swt[r][0]);
        float4 w1 = *(const float4*)(&swt[r][4]);
        F3 xv = *(const F3*)(xb + r * C_ + c0);
        acc[0][0] = fmaf(w0.x, xv.x, acc[0][0]);
        acc[0][1] = fmaf(w0.x, xv.y, acc[0][1]);
        acc[0][2] = fmaf(w0.x, xv.z, acc[0][2]);
        acc[1][0] = fmaf(w0.y, xv.x, acc[1][0]);
        acc[1][1] = fmaf(w0.y, xv.y, acc[1][1]);
        acc[1][2] = fmaf(w0.y, xv.z, acc[1][2]);
        acc[2][0] = fmaf(w0.z, xv.x, acc[2][0]);
        acc[2][1] = fmaf(w0.z, xv.y, acc[2][1]);
        acc[2][2] = fmaf(w0.z, xv.z, acc[2][2]);
        acc[3][0] = fmaf(w0.w, xv.x, acc[3][0]);
        acc[3][1] = fmaf(w0.w, xv.y, acc[3][1]);
        acc[3][2] = fmaf(w0.w, xv.z, acc[3][2]);
        acc[4][0] = fmaf(w1.x, xv.x, acc[4][0]);
        acc[4][1] = fmaf(w1.x, xv.y, acc[4][1]);
        acc[4][2] = fmaf(w1.x, xv.z, acc[4][2]);
        acc[5][0] = fmaf(w1.y, xv.x, acc[5][0]);
        acc[5][1] = fmaf(w1.y, xv.y, acc[5][1]);
        acc[5][2] = fmaf(w1.y, xv.z, acc[5][2]);
        acc[6][0] = fmaf(w1.z, xv.x, acc[6][0]);
        acc[6][1] = fmaf(w1.z, xv.y, acc[6][1]);
        acc[6][2] = fmaf(w1.z, xv.z, acc[6][2]);
        acc[7][0] = fmaf(w1.w, xv.x, acc[7][0]);
        acc[7][1] = fmaf(w1.w, xv.y, acc[7][1]);
        acc[7][2] = fmaf(w1.w, xv.z, acc[7][2]);
      }
    }
  }

  // ---- epilogue: chunk partials + denominators ------------------------------
  {
    const int c0 = tid * 3;
    float* pp = part + ((size_t)(b * NCH + ch) * H_) * C_ + c0;
#pragma unroll
    for (int h = 0; h < H_; ++h) {
      F3 o = { acc[h][0], acc[h][1], acc[h][2] };
      *(F3*)(pp + (size_t)h * C_) = o;
    }
    if (lane < 2) sout[(size_t)(b * NCH + ch) * H_ + h0 + lane] = sreg;
  }
#undef STAGE
}

// ---- combine chunk partials -> xbar = sum part / sum s --------------------
__global__ __launch_bounds__(256) void k_comb(const float* __restrict__ part,
    const float* __restrict__ spart, float* __restrict__ xbar) {
  int i = blockIdx.x * 256 + threadIdx.x;   // < B*H*C
  int bh = i / C_;
  int c  = i - bh * C_;
  int b = bh / H_, h = bh - b * H_;
  const float* sp = spart + (size_t)b * NCH * H_ + h;
  const float* pp = part + ((size_t)b * NCH * H_ + h) * C_ + c;
  float denom = 0.f, acc = 0.f;
#pragma unroll 4
  for (int ch = 0; ch < NCH; ++ch) {
    denom += sp[(size_t)ch * H_];
    acc   += pp[(size_t)ch * H_ * C_];
  }
  xbar[i] = acc / denom;
}

// ---- out1[b,e] = sum_c xbar[b, e/DH, c] * Wkv[C+e, c] ---------------------
__global__ __launch_bounds__(256) void k_out1(const float* __restrict__ xbar,
    const float* __restrict__ Wkv, float* __restrict__ out1) {
  int wv = threadIdx.x >> 6, lane = threadIdx.x & 63;
  int e0 = blockIdx.x * 64 + wv * 16;
  int b0 = blockIdx.y * 8;
  for (int it = 0; it < 16; ++it) {
    int e = e0 + it;
    int h = e / DH_;
    const float* wr = Wkv + (size_t)(C_ + e) * C_ + lane * 4;
    float4 w0 = *(const float4*)(wr);
    float4 w1 = *(const float4*)(wr + 256);
    float4 w2 = *(const float4*)(wr + 512);
    for (int bb = 0; bb < 8; ++bb) {
      int b = b0 + bb;
      const float* xr = xbar + ((size_t)b * H_ + h) * C_ + lane * 4;
      float4 x0 = *(const float4*)(xr);
      float4 x1 = *(const float4*)(xr + 256);
      float4 x2 = *(const float4*)(xr + 512);
      float a = w0.x * x0.x;
      a = fmaf(w0.y, x0.y, a); a = fmaf(w0.z, x0.z, a); a = fmaf(w0.w, x0.w, a);
      a = fmaf(w1.x, x1.x, a); a = fmaf(w1.y, x1.y, a);
      a = fmaf(w1.z, x1.z, a); a = fmaf(w1.w, x1.w, a);
      a = fmaf(w2.x, x2.x, a); a = fmaf(w2.y, x2.y, a);
      a = fmaf(w2.z, x2.z, a); a = fmaf(w2.w, x2.w, a);
#pragma unroll
      for (int off = 32; off; off >>= 1) a += __shfl_xor(a, off);
      if (lane == 0) out1[(size_t)b * C_ + e] = a;
    }
  }
}

// ---- y[b,e] = sum_c out1[b,c] * Wproj[e,c] + bproj[e] ---------------------
__global__ __launch_bounds__(256) void k_proj(const float* __restrict__ out1,
    const float* __restrict__ Wproj, const float* __restrict__ bproj,
    float* __restrict__ y) {
  int wv = threadIdx.x >> 6, lane = threadIdx.x & 63;
  int e0 = blockIdx.x * 64 + wv * 16;
  int b0 = blockIdx.y * 8;
  for (int it = 0; it < 16; ++it) {
    int e = e0 + it;
    const float* wr = Wproj + (size_t)e * C_ + lane * 4;
    float4 w0 = *(const float4*)(wr);
    float4 w1 = *(const float4*)(wr + 256);
    float4 w2 = *(const float4*)(wr + 512);
    for (int bb = 0; bb < 8; ++bb) {
      int b = b0 + bb;
      const float* xr = out1 + (size_t)b * C_ + lane * 4;
      float4 x0 = *(const float4*)(xr);
      float4 x1 = *(const float4*)(xr + 256);
      float4 x2 = *(const float4*)(xr + 512);
      float a = w0.x * x0.x;
      a = fmaf(w0.y, x0.y, a); a = fmaf(w0.z, x0.z, a); a = fmaf(w0.w, x0.w, a);
      a = fmaf(w1.x, x1.x, a); a = fmaf(w1.y, x1.y, a);
      a = fmaf(w1.z, x1.z, a); a = fmaf(w1.w, x1.w, a);
      a = fmaf(w2.x, x2.x, a); a = fmaf(w2.y, x2.y, a);
      a = fmaf(w2.z, x2.z, a); a = fmaf(w2.w, x2.w, a);
#pragma unroll
      for (int off = 32; off; off >>= 1) a += __shfl_xor(a, off);
      if (lane == 0) y[(size_t)b * C_ + e] = a + bproj[e];
    }
  }
}

extern "C" void kernel_launch(void* const* d_in, const int* in_sizes, int n_in,
                              void* d_out, int out_size, void* d_ws, size_t ws_size,
                              hipStream_t stream) {
  const float* x       = (const float*)d_in[0];
  const float* queries = (const float*)d_in[1];
  const float* Wq      = (const float*)d_in[2];
  const float* Wkv     = (const float*)d_in[3];
  const float* Wproj   = (const float*)d_in[4];
  const float* bproj   = (const float*)d_in[5];
  float* y  = (float*)d_out;
  float* ws = (float*)d_ws;

  float* q     = ws;                                   // 768
  float* wqe   = ws + 1024;                            // 6144
  float* spart = ws + 8192;                            // B*NCH*H = 8192
  float* part  = ws + 16384;                           // B*NCH*H*C = 6291456
  float* xbar  = part + (size_t)B_ * NCH * H_ * C_;    // 196608
  float* out1  = xbar + (size_t)B_ * H_ * C_;          // 24576

  hipLaunchKernelGGL(k_q,     dim3(C_),            dim3(64),  0, stream, queries, Wq, q);
  hipLaunchKernelGGL(k_wqeff, dim3(H_ * C_ / 256), dim3(256), 0, stream, q, Wkv, wqe);
  hipLaunchKernelGGL(k_fused, dim3(NCH, B_),       dim3(256), 0, stream, x, wqe, part, spart);
  hipLaunchKernelGGL(k_comb,  dim3(B_ * H_ * C_ / 256), dim3(256), 0, stream, part, spart, xbar);
  hipLaunchKernelGGL(k_out1,  dim3(12, 4),         dim3(256), 0, stream, xbar, Wkv, out1);
  hipLaunchKernelGGL(k_proj,  dim3(12, 4),         dim3(256), 0, stream, out1, Wproj, bproj, y);
}

// Round 8
// 244.934 us; speedup vs baseline: 1.0994x; 1.0994x over previous
//
#include <hip/hip_runtime.h>

// Problem constants
#define B_ 32
#define N_ 4096
#define C_ 768
#define H_ 8
#define DH_ 96
#define TILE 8
#define ROWS 128
#define NT (ROWS / TILE)     // 16 tiles per chunk
#define NCH (N_ / ROWS)      // 32 chunks per batch row

struct F3 { float x, y, z; };

#define BARL() do { asm volatile("s_waitcnt lgkmcnt(0)" ::: "memory"); \
                    __builtin_amdgcn_s_barrier(); } while (0)

// ---- q[e] = sum_c queries[c] * Wq[e,c] ------------------------------------
__global__ void k_q(const float* __restrict__ queries, const float* __restrict__ Wq,
                    float* __restrict__ q) {
  int e = blockIdx.x;
  int lane = threadIdx.x;
  const float* row = Wq + (size_t)e * C_;
  float acc = 0.f;
#pragma unroll
  for (int p = 0; p < 3; ++p) {
    int c = p * 256 + lane * 4;
    float4 w = *(const float4*)(row + c);
    float4 qa = *(const float4*)(queries + c);
    acc += w.x * qa.x + w.y * qa.y + w.z * qa.z + w.w * qa.w;
  }
#pragma unroll
  for (int off = 32; off; off >>= 1) acc += __shfl_xor(acc, off);
  if (lane == 0) q[e] = acc;
}

// ---- wq_eff[h,c] = sum_d q[h*DH+d] * Wkv[h*DH+d, c] -----------------------
__global__ void k_wqeff(const float* __restrict__ q, const float* __restrict__ Wkv,
                        float* __restrict__ wqe) {
  int i = blockIdx.x * 256 + threadIdx.x;
  int h = i / C_;
  int c = i - h * C_;
  const float* qh = q + h * DH_;
  float acc = 0.f;
  for (int d = 0; d < DH_; ++d)
    acc = fmaf(qh[d], Wkv[(size_t)(h * DH_ + d) * C_ + c], acc);
  wqe[i] = acc;
}

// ---- single-pass fused: dots -> exp(d-20) -> weighted accumulate ----------
// grid (NCH, B_) = 1024 blocks, 256 threads, 48.3 KB LDS -> 3 blocks/CU.
// Wave wid owns rows {(wid&1)*4..+3} x heads {(wid>>1)*4..+3} in phase A:
// dots LDS-read redundancy 2x (vs 4x in R7), 24 shfl/wave/tile (vs 48).
__global__ __launch_bounds__(256, 3) void k_fused(
    const float* __restrict__ x, const float* __restrict__ wqe,
    float* __restrict__ part, float* __restrict__ sout) {
  __shared__ __align__(16) float xbuf[2][TILE * C_];  // 48 KB double buffer
  __shared__ __align__(16) float wlds[TILE][H_];      // exp weights
  __shared__ float sden[4][4];                        // epilogue denominators

  const int ch = blockIdx.x, b = blockIdx.y;
  const int tid = threadIdx.x, lane = tid & 63, wid = tid >> 6;
  const int rbase = (wid & 1) * 4;
  const int hbase = (wid >> 1) * 4;
  const int col12 = lane * 12;       // phase A: lane owns 12 contiguous cols
  const float* xc = x + ((size_t)b * N_ + (size_t)ch * ROWS) * C_;

  // wq for this wave's 4 heads over lane's 12 cols: 48 VGPR
  float4 wqv[4][3];
#pragma unroll
  for (int h = 0; h < 4; ++h)
#pragma unroll
    for (int p = 0; p < 3; ++p)
      wqv[h][p] = *(const float4*)(wqe + (size_t)(hbase + h) * C_ + col12 + p * 4);

  // phase C accumulator: thread owns cols {tid*3..+2} for all 8 heads
  float acc[H_][3];
#pragma unroll
  for (int h = 0; h < H_; ++h) { acc[h][0] = 0.f; acc[h][1] = 0.f; acc[h][2] = 0.f; }
  float sreg = 0.f;   // lanes 0-3: denom partial for head hbase+lane, rows rbase..+3

#define STAGE(BUF, T) do {                                                     \
    const float* gt_ = xc + (size_t)(T) * TILE * C_;                           \
    float* bn_ = xbuf[BUF];                                                    \
    _Pragma("unroll")                                                          \
    for (int j = 0; j < 6; ++j) {                                              \
      int k = wid * 6 + j;                                                     \
      __builtin_amdgcn_global_load_lds(                                        \
        (const __attribute__((address_space(1))) void*)(gt_ + k * 256 + lane * 4), \
        (__attribute__((address_space(3))) void*)(bn_ + k * 256),              \
        16, 0, 0);                                                             \
    }                                                                          \
  } while (0)

  STAGE(0, 0);   // prologue

  for (int t = 0; t < NT; ++t) {
    const float* xb = xbuf[t & 1];
    asm volatile("s_waitcnt vmcnt(0)" ::: "memory");  // own tile-t loads done
    BARL();                                           // all waves staged; C(t-1) done
    if (t + 1 < NT) STAGE((t + 1) & 1, t + 1);        // covered by A+C of tile t

    // ---- Phase A: 4 rows x 4 heads -----------------------------------------
#pragma unroll
    for (int rr = 0; rr < 4; ++rr) {
      const int r = rbase + rr;
      const float* xr = xb + r * C_ + col12;
      float4 xv0 = *(const float4*)(xr);
      float4 xv1 = *(const float4*)(xr + 4);
      float4 xv2 = *(const float4*)(xr + 8);
      float d[4];
#pragma unroll
      for (int h = 0; h < 4; ++h) {
        float a = xv0.x * wqv[h][0].x;
        a = fmaf(xv0.y, wqv[h][0].y, a);
        a = fmaf(xv0.z, wqv[h][0].z, a);
        a = fmaf(xv0.w, wqv[h][0].w, a);
        a = fmaf(xv1.x, wqv[h][1].x, a);
        a = fmaf(xv1.y, wqv[h][1].y, a);
        a = fmaf(xv1.z, wqv[h][1].z, a);
        a = fmaf(xv1.w, wqv[h][1].w, a);
        a = fmaf(xv2.x, wqv[h][2].x, a);
        a = fmaf(xv2.y, wqv[h][2].y, a);
        a = fmaf(xv2.z, wqv[h][2].z, a);
        a = fmaf(xv2.w, wqv[h][2].w, a);
        d[h] = a;
      }
      // packed-4 reduce: lane ends with head hbase+(lane&3) full dot
      const int s1 = lane & 1, s2 = lane & 2;
      float A0 = (s1 ? d[1] : d[0]) + __shfl_xor(s1 ? d[0] : d[1], 1);
      float A1 = (s1 ? d[3] : d[2]) + __shfl_xor(s1 ? d[2] : d[3], 1);
      float Q  = (s2 ? A1 : A0) + __shfl_xor(s2 ? A0 : A1, 2);
      Q += __shfl_xor(Q, 4);
      Q += __shfl_xor(Q, 8);
      Q += __shfl_xor(Q, 16);
      Q += __shfl_xor(Q, 32);
      float w = __expf(Q - 20.f);
      if (lane < 4) { wlds[r][hbase + lane] = w; sreg += w; }
    }
    BARL();   // wlds published

    // ---- Phase C: acc[h][c-slice] += sum_r wlds[r][h] * x[r][c-slice] ------
    {
      const int c0 = tid * 3;
#pragma unroll
      for (int r = 0; r < TILE; ++r) {
        float4 wA = *(const float4*)(&wlds[r][0]);   // broadcast (free)
        float4 wB = *(const float4*)(&wlds[r][4]);
        F3 xv = *(const F3*)(xb + r * C_ + c0);
        acc[0][0] = fmaf(wA.x, xv.x, acc[0][0]);
        acc[0][1] = fmaf(wA.x, xv.y, acc[0][1]);
        acc[0][2] = fmaf(wA.x, xv.z, acc[0][2]);
        acc[1][0] = fmaf(wA.y, xv.x, acc[1][0]);
        acc[1][1] = fmaf(wA.y, xv.y, acc[1][1]);
        acc[1][2] = fmaf(wA.y, xv.z, acc[1][2]);
        acc[2][0] = fmaf(wA.z, xv.x, acc[2][0]);
        acc[2][1] = fmaf(wA.z, xv.y, acc[2][1]);
        acc[2][2] = fmaf(wA.z, xv.z, acc[2][2]);
        acc[3][0] = fmaf(wA.w, xv.x, acc[3][0]);
        acc[3][1] = fmaf(wA.w, xv.y, acc[3][1]);
        acc[3][2] = fmaf(wA.w, xv.z, acc[3][2]);
        acc[4][0] = fmaf(wB.x, xv.x, acc[4][0]);
        acc[4][1] = fmaf(wB.x, xv.y, acc[4][1]);
        acc[4][2] = fmaf(wB.x, xv.z, acc[4][2]);
        acc[5][0] = fmaf(wB.y, xv.x, acc[5][0]);
        acc[5][1] = fmaf(wB.y, xv.y, acc[5][1]);
        acc[5][2] = fmaf(wB.y, xv.z, acc[5][2]);
        acc[6][0] = fmaf(wB.z, xv.x, acc[6][0]);
        acc[6][1] = fmaf(wB.z, xv.y, acc[6][1]);
        acc[6][2] = fmaf(wB.z, xv.z, acc[6][2]);
        acc[7][0] = fmaf(wB.w, xv.x, acc[7][0]);
        acc[7][1] = fmaf(wB.w, xv.y, acc[7][1]);
        acc[7][2] = fmaf(wB.w, xv.z, acc[7][2]);
      }
    }
  }

  // ---- epilogue: chunk partials + denominators ------------------------------
  {
    const int c0 = tid * 3;
    float* pp = part + ((size_t)(b * NCH + ch) * H_) * C_ + c0;
#pragma unroll
    for (int h = 0; h < H_; ++h) {
      F3 o = { acc[h][0], acc[h][1], acc[h][2] };
      *(F3*)(pp + (size_t)h * C_) = o;
    }
    if (lane < 4) sden[wid][lane] = sreg;
    BARL();
    if (tid < H_) {
      int hh = tid >> 2;   // head half
      float den = sden[2 * hh][tid & 3] + sden[2 * hh + 1][tid & 3];
      sout[(size_t)(b * NCH + ch) * H_ + tid] = den;
    }
  }
#undef STAGE
}

// ---- combine chunk partials -> xbar = sum part / sum s --------------------
__global__ __launch_bounds__(256) void k_comb(const float* __restrict__ part,
    const float* __restrict__ spart, float* __restrict__ xbar) {
  int i = blockIdx.x * 256 + threadIdx.x;   // < B*H*C
  int bh = i / C_;
  int c  = i - bh * C_;
  int b = bh / H_, h = bh - b * H_;
  const float* sp = spart + (size_t)b * NCH * H_ + h;
  const float* pp = part + ((size_t)b * NCH * H_ + h) * C_ + c;
  float denom = 0.f, acc = 0.f;
#pragma unroll 4
  for (int ch = 0; ch < NCH; ++ch) {
    denom += sp[(size_t)ch * H_];
    acc   += pp[(size_t)ch * H_ * C_];
  }
  xbar[i] = acc / denom;
}

// ---- out1[b,e] = sum_c xbar[b, e/DH, c] * Wkv[C+e, c] ---------------------
__global__ __launch_bounds__(256) void k_out1(const float* __restrict__ xbar,
    const float* __restrict__ Wkv, float* __restrict__ out1) {
  int wv = threadIdx.x >> 6, lane = threadIdx.x & 63;
  int e0 = blockIdx.x * 64 + wv * 16;
  int b0 = blockIdx.y * 8;
  for (int it = 0; it < 16; ++it) {
    int e = e0 + it;
    int h = e / DH_;
    const float* wr = Wkv + (size_t)(C_ + e) * C_ + lane * 4;
    float4 w0 = *(const float4*)(wr);
    float4 w1 = *(const float4*)(wr + 256);
    float4 w2 = *(const float4*)(wr + 512);
    for (int bb = 0; bb < 8; ++bb) {
      int b = b0 + bb;
      const float* xr = xbar + ((size_t)b * H_ + h) * C_ + lane * 4;
      float4 x0 = *(const float4*)(xr);
      float4 x1 = *(const float4*)(xr + 256);
      float4 x2 = *(const float4*)(xr + 512);
      float a = w0.x * x0.x;
      a = fmaf(w0.y, x0.y, a); a = fmaf(w0.z, x0.z, a); a = fmaf(w0.w, x0.w, a);
      a = fmaf(w1.x, x1.x, a); a = fmaf(w1.y, x1.y, a);
      a = fmaf(w1.z, x1.z, a); a = fmaf(w1.w, x1.w, a);
      a = fmaf(w2.x, x2.x, a); a = fmaf(w2.y, x2.y, a);
      a = fmaf(w2.z, x2.z, a); a = fmaf(w2.w, x2.w, a);
#pragma unroll
      for (int off = 32; off; off >>= 1) a += __shfl_xor(a, off);
      if (lane == 0) out1[(size_t)b * C_ + e] = a;
    }
  }
}

// ---- y[b,e] = sum_c out1[b,c] * Wproj[e,c] + bproj[e] ---------------------
__global__ __launch_bounds__(256) void k_proj(const float* __restrict__ out1,
    const float* __restrict__ Wproj, const float* __restrict__ bproj,
    float* __restrict__ y) {
  int wv = threadIdx.x >> 6, lane = threadIdx.x & 63;
  int e0 = blockIdx.x * 64 + wv * 16;
  int b0 = blockIdx.y * 8;
  for (int it = 0; it < 16; ++it) {
    int e = e0 + it;
    const float* wr = Wproj + (size_t)e * C_ + lane * 4;
    float4 w0 = *(const float4*)(wr);
    float4 w1 = *(const float4*)(wr + 256);
    float4 w2 = *(const float4*)(wr + 512);
    for (int bb = 0; bb < 8; ++bb) {
      int b = b0 + bb;
      const float* xr = out1 + (size_t)b * C_ + lane * 4;
      float4 x0 = *(const float4*)(xr);
      float4 x1 = *(const float4*)(xr + 256);
      float4 x2 = *(const float4*)(xr + 512);
      float a = w0.x * x0.x;
      a = fmaf(w0.y, x0.y, a); a = fmaf(w0.z, x0.z, a); a = fmaf(w0.w, x0.w, a);
      a = fmaf(w1.x, x1.x, a); a = fmaf(w1.y, x1.y, a);
      a = fmaf(w1.z, x1.z, a); a = fmaf(w1.w, x1.w, a);
      a = fmaf(w2.x, x2.x, a); a = fmaf(w2.y, x2.y, a);
      a = fmaf(w2.z, x2.z, a); a = fmaf(w2.w, x2.w, a);
#pragma unroll
      for (int off = 32; off; off >>= 1) a += __shfl_xor(a, off);
      if (lane == 0) y[(size_t)b * C_ + e] = a + bproj[e];
    }
  }
}

extern "C" void kernel_launch(void* const* d_in, const int* in_sizes, int n_in,
                              void* d_out, int out_size, void* d_ws, size_t ws_size,
                              hipStream_t stream) {
  const float* x       = (const float*)d_in[0];
  const float* queries = (const float*)d_in[1];
  const float* Wq      = (const float*)d_in[2];
  const float* Wkv     = (const float*)d_in[3];
  const float* Wproj   = (const float*)d_in[4];
  const float* bproj   = (const float*)d_in[5];
  float* y  = (float*)d_out;
  float* ws = (float*)d_ws;

  float* q     = ws;                                   // 768
  float* wqe   = ws + 1024;                            // 6144
  float* spart = ws + 8192;                            // B*NCH*H = 8192
  float* part  = ws + 16384;                           // B*NCH*H*C = 6291456
  float* xbar  = part + (size_t)B_ * NCH * H_ * C_;    // 196608
  float* out1  = xbar + (size_t)B_ * H_ * C_;          // 24576

  hipLaunchKernelGGL(k_q,     dim3(C_),            dim3(64),  0, stream, queries, Wq, q);
  hipLaunchKernelGGL(k_wqeff, dim3(H_ * C_ / 256), dim3(256), 0, stream, q, Wkv, wqe);
  hipLaunchKernelGGL(k_fused, dim3(NCH, B_),       dim3(256), 0, stream, x, wqe, part, spart);
  hipLaunchKernelGGL(k_comb,  dim3(B_ * H_ * C_ / 256), dim3(256), 0, stream, part, spart, xbar);
  hipLaunchKernelGGL(k_out1,  dim3(12, 4),         dim3(256), 0, stream, xbar, Wkv, out1);
  hipLaunchKernelGGL(k_proj,  dim3(12, 4),         dim3(256), 0, stream, out1, Wproj, bproj, y);
}